// Round 3
// baseline (298.776 us; speedup 1.0000x reference)
//
#include <hip/hip_runtime.h>
#include <hip/hip_bf16.h>

// SDPA causal, B=2 H=16 S=2048 D=64, scale=8. Outputs: attn(f32) ++ out(f32).
// R3: barrier-free 1-wave blocks (4096x64), K/V pre-converted to bf16 in d_ws
// (V transposed), direct-from-L2 fragment loads, heavy-first launch order.
#define S_LEN 2048
#define D_HEAD 64

typedef __attribute__((ext_vector_type(8))) short short8;   // 8 bf16 MFMA A/B frag
typedef __attribute__((ext_vector_type(4))) float f32x4;    // MFMA C/D frag

__device__ __forceinline__ unsigned short f2b(float f) {    // fp32 -> bf16 (RNE)
  unsigned int u = __float_as_uint(f);
  u += 0x7fffu + ((u >> 16) & 1u);
  return (unsigned short)(u >> 16);
}

// ---- pre-convert: K -> bf16 (same layout), V -> bf16 transposed [bh][d][s] ----
__global__ __launch_bounds__(256) void convert_kv_kernel(
    const float* __restrict__ K, const float* __restrict__ V,
    unsigned short* __restrict__ Kb, unsigned short* __restrict__ Vt) {
  int b = blockIdx.x;
  if (b < 2048) {  // K elementwise: 2048 blocks x 256 thr x 8 elems = 4.19M
    size_t base = ((size_t)b * 256 + threadIdx.x) * 8;
    float4 x0 = *(const float4*)(K + base);
    float4 x1 = *(const float4*)(K + base + 4);
    short8 o;
    o[0]=(short)f2b(x0.x); o[1]=(short)f2b(x0.y); o[2]=(short)f2b(x0.z); o[3]=(short)f2b(x0.w);
    o[4]=(short)f2b(x1.x); o[5]=(short)f2b(x1.y); o[6]=(short)f2b(x1.z); o[7]=(short)f2b(x1.w);
    *(short8*)(Kb + base) = o;
  } else {         // V transpose: 2048 blocks = 32 bh x 64 s-chunks of 32
    int idx = b - 2048;
    int bh = idx >> 6, sc = idx & 63;
    int lane = threadIdx.x & 63;          // = d
    int w = threadIdx.x >> 6;
    int sb = sc * 32 + w * 8;
    const float* vp = V + (size_t)bh * (S_LEN * D_HEAD) + (size_t)sb * D_HEAD + lane;
    short8 o;
    #pragma unroll
    for (int i = 0; i < 8; ++i) o[i] = (short)f2b(vp[i * D_HEAD]);  // coalesced per i
    *(short8*)(Vt + (size_t)bh * (S_LEN * D_HEAD) + (size_t)lane * S_LEN + sb) = o;
  }
}

template<bool PRE>
__device__ __forceinline__ void loadKfrag(const unsigned short* KbP, const float* KgP,
                                          int row, int g, short8& lo, short8& hi) {
  if (PRE) {
    const unsigned short* p = KbP + row * 64 + g * 8;
    lo = *(const short8*)p;
    hi = *(const short8*)(p + 32);
  } else {
    const float* p = KgP + (size_t)row * 64 + g * 8;
    float4 a = *(const float4*)p,        b2 = *(const float4*)(p + 4);
    float4 c2 = *(const float4*)(p + 32), d2 = *(const float4*)(p + 36);
    lo[0]=(short)f2b(a.x); lo[1]=(short)f2b(a.y); lo[2]=(short)f2b(a.z); lo[3]=(short)f2b(a.w);
    lo[4]=(short)f2b(b2.x); lo[5]=(short)f2b(b2.y); lo[6]=(short)f2b(b2.z); lo[7]=(short)f2b(b2.w);
    hi[0]=(short)f2b(c2.x); hi[1]=(short)f2b(c2.y); hi[2]=(short)f2b(c2.z); hi[3]=(short)f2b(c2.w);
    hi[4]=(short)f2b(d2.x); hi[5]=(short)f2b(d2.y); hi[6]=(short)f2b(d2.z); hi[7]=(short)f2b(d2.w);
  }
}

template<bool PRE>
__global__ __launch_bounds__(64, 4) void sdpa_1wave_kernel(
    const float* __restrict__ Qg, const float* __restrict__ Kg,
    const float* __restrict__ Vg, const unsigned short* __restrict__ Kb,
    const unsigned short* __restrict__ Vt, float* __restrict__ attn,
    float* __restrict__ outp) {
  const int b = blockIdx.x;
  const int r = 127 - (b >> 5);   // 16-row q-tile, heavy-first
  const int bh = b & 31;          // bh -> XCD (b mod 8 stable for fixed bh): K/V L2-resident

  const int lane = threadIdx.x;
  const int g = lane >> 4;        // 0..3
  const int m = lane & 15;        // 0..15

  __shared__ __align__(16) unsigned short Pl[16 * 32];  // per-wave P tile, 1KB
  char* const PlB = (char*)Pl;

  const size_t bhSD = (size_t)bh * (S_LEN * D_HEAD);
  const size_t bhSS = (size_t)bh << 22;   // *S*S
  const unsigned short* KbP = Kb + bhSD;
  const unsigned short* VtP = Vt + bhSD;
  const float* KgP = Kg + bhSD;

  const int q0 = r << 4;
  const int nC = (r + 2) >> 1;            // 32-col chunks covering kmax=16(r+1)
  const int row0 = q0 + 4 * g;            // C-frag rows row0+reg

  // ---- Q A-fragments (pre-scaled by log2(e)/8; exp -> exp2) ----
  const float SCL = 0.18033688011112042f;
  short8 aq0, aq1;
  {
    const float* qp = Qg + bhSD + (size_t)(q0 + m) * D_HEAD + g * 8;
    float4 x0 = *(const float4*)(qp);
    float4 x1 = *(const float4*)(qp + 4);
    float4 y0 = *(const float4*)(qp + 32);
    float4 y1 = *(const float4*)(qp + 36);
    aq0[0]=(short)f2b(x0.x*SCL); aq0[1]=(short)f2b(x0.y*SCL);
    aq0[2]=(short)f2b(x0.z*SCL); aq0[3]=(short)f2b(x0.w*SCL);
    aq0[4]=(short)f2b(x1.x*SCL); aq0[5]=(short)f2b(x1.y*SCL);
    aq0[6]=(short)f2b(x1.z*SCL); aq0[7]=(short)f2b(x1.w*SCL);
    aq1[0]=(short)f2b(y0.x*SCL); aq1[1]=(short)f2b(y0.y*SCL);
    aq1[2]=(short)f2b(y0.z*SCL); aq1[3]=(short)f2b(y0.w*SCL);
    aq1[4]=(short)f2b(y1.x*SCL); aq1[5]=(short)f2b(y1.y*SCL);
    aq1[6]=(short)f2b(y1.z*SCL); aq1[7]=(short)f2b(y1.w*SCL);
  }

  // ================= Pass 1: row sums of exp =================
  float rs0 = 0.f, rs1 = 0.f, rs2 = 0.f, rs3 = 0.f;
  for (int c = 0; c < nC; ++c) {
    const int kc = c << 5;
    short8 b00, b01, b10, b11;
    loadKfrag<PRE>(KbP, KgP, kc + m, g, b00, b01);
    loadKfrag<PRE>(KbP, KgP, kc + 16 + m, g, b10, b11);
    f32x4 a0 = {0.f,0.f,0.f,0.f}, a1 = {0.f,0.f,0.f,0.f};
    a0 = __builtin_amdgcn_mfma_f32_16x16x32_bf16(aq0, b00, a0, 0, 0, 0);
    a0 = __builtin_amdgcn_mfma_f32_16x16x32_bf16(aq1, b01, a0, 0, 0, 0);
    a1 = __builtin_amdgcn_mfma_f32_16x16x32_bf16(aq0, b10, a1, 0, 0, 0);
    a1 = __builtin_amdgcn_mfma_f32_16x16x32_bf16(aq1, b11, a1, 0, 0, 0);
    const int c0 = kc + m, c1 = kc + 16 + m;
    rs0 += ((c0 <= row0 + 0) ? exp2f(a0[0]) : 0.f) + ((c1 <= row0 + 0) ? exp2f(a1[0]) : 0.f);
    rs1 += ((c0 <= row0 + 1) ? exp2f(a0[1]) : 0.f) + ((c1 <= row0 + 1) ? exp2f(a1[1]) : 0.f);
    rs2 += ((c0 <= row0 + 2) ? exp2f(a0[2]) : 0.f) + ((c1 <= row0 + 2) ? exp2f(a1[2]) : 0.f);
    rs3 += ((c0 <= row0 + 3) ? exp2f(a0[3]) : 0.f) + ((c1 <= row0 + 3) ? exp2f(a1[3]) : 0.f);
  }
  #pragma unroll
  for (int sft = 1; sft < 16; sft <<= 1) {
    rs0 += __shfl_xor(rs0, sft, 64);
    rs1 += __shfl_xor(rs1, sft, 64);
    rs2 += __shfl_xor(rs2, sft, 64);
    rs3 += __shfl_xor(rs3, sft, 64);
  }
  const float ri0 = 1.f / rs0, ri1 = 1.f / rs1, ri2 = 1.f / rs2, ri3 = 1.f / rs3;

  // ================= Pass 2: recompute, write attn, accumulate O =========
  f32x4 o0 = {0.f,0.f,0.f,0.f}, o1 = {0.f,0.f,0.f,0.f};
  f32x4 o2 = {0.f,0.f,0.f,0.f}, o3 = {0.f,0.f,0.f,0.f};
  const int swzW = g << 5;                 // P write swizzle ((row>>2)&3)<<5, row=4g+j
  const int swzR = ((m >> 2) & 3) << 5;    // P read swizzle, row=m
  float* const abase = attn + bhSS + (size_t)row0 * S_LEN;

  for (int c = 0; c < nC; ++c) {
    const int kc = c << 5;
    short8 b00, b01, b10, b11;
    loadKfrag<PRE>(KbP, KgP, kc + m, g, b00, b01);
    loadKfrag<PRE>(KbP, KgP, kc + 16 + m, g, b10, b11);
    f32x4 a0 = {0.f,0.f,0.f,0.f}, a1 = {0.f,0.f,0.f,0.f};
    a0 = __builtin_amdgcn_mfma_f32_16x16x32_bf16(aq0, b00, a0, 0, 0, 0);
    a0 = __builtin_amdgcn_mfma_f32_16x16x32_bf16(aq1, b01, a0, 0, 0, 0);
    a1 = __builtin_amdgcn_mfma_f32_16x16x32_bf16(aq0, b10, a1, 0, 0, 0);
    a1 = __builtin_amdgcn_mfma_f32_16x16x32_bf16(aq1, b11, a1, 0, 0, 0);
    const int c0 = kc + m, c1 = kc + 16 + m;
    float p00 = (c0 <= row0 + 0) ? exp2f(a0[0]) * ri0 : 0.f;
    float p01 = (c0 <= row0 + 1) ? exp2f(a0[1]) * ri1 : 0.f;
    float p02 = (c0 <= row0 + 2) ? exp2f(a0[2]) * ri2 : 0.f;
    float p03 = (c0 <= row0 + 3) ? exp2f(a0[3]) * ri3 : 0.f;
    float p10 = (c1 <= row0 + 0) ? exp2f(a1[0]) * ri0 : 0.f;
    float p11 = (c1 <= row0 + 1) ? exp2f(a1[1]) * ri1 : 0.f;
    float p12 = (c1 <= row0 + 2) ? exp2f(a1[2]) * ri2 : 0.f;
    float p13 = (c1 <= row0 + 3) ? exp2f(a1[3]) * ri3 : 0.f;
    // attn stores (4 rows x 2 cols per lane)
    float* ap = abase + kc;
    ap[0 * S_LEN + m] = p00;  ap[0 * S_LEN + 16 + m] = p10;
    ap[1 * S_LEN + m] = p01;  ap[1 * S_LEN + 16 + m] = p11;
    ap[2 * S_LEN + m] = p02;  ap[2 * S_LEN + 16 + m] = p12;
    ap[3 * S_LEN + m] = p03;  ap[3 * S_LEN + 16 + m] = p13;
    // P -> LDS transpose (per-wave, swizzled; 2-way max = free)
    const int rb = g << 8;  // (4g)*64 bytes
    *(unsigned short*)(PlB + ((rb + 0 * 64 + 2 * m     ) ^ swzW)) = f2b(p00);
    *(unsigned short*)(PlB + ((rb + 1 * 64 + 2 * m     ) ^ swzW)) = f2b(p01);
    *(unsigned short*)(PlB + ((rb + 2 * 64 + 2 * m     ) ^ swzW)) = f2b(p02);
    *(unsigned short*)(PlB + ((rb + 3 * 64 + 2 * m     ) ^ swzW)) = f2b(p03);
    *(unsigned short*)(PlB + ((rb + 0 * 64 + 2 * m + 32) ^ swzW)) = f2b(p10);
    *(unsigned short*)(PlB + ((rb + 1 * 64 + 2 * m + 32) ^ swzW)) = f2b(p11);
    *(unsigned short*)(PlB + ((rb + 2 * 64 + 2 * m + 32) ^ swzW)) = f2b(p12);
    *(unsigned short*)(PlB + ((rb + 3 * 64 + 2 * m + 32) ^ swzW)) = f2b(p13);
    // PV
    short8 pa = *(const short8*)(PlB + ((m * 64 + g * 16) ^ swzR));
    short8 bv0, bv1, bv2, bv3;
    if (PRE) {
      bv0 = *(const short8*)(VtP + (size_t)( 0 + m) * S_LEN + kc + g * 8);
      bv1 = *(const short8*)(VtP + (size_t)(16 + m) * S_LEN + kc + g * 8);
      bv2 = *(const short8*)(VtP + (size_t)(32 + m) * S_LEN + kc + g * 8);
      bv3 = *(const short8*)(VtP + (size_t)(48 + m) * S_LEN + kc + g * 8);
    } else {
      const float* vg = Vg + bhSD + (size_t)(kc + g * 8) * D_HEAD + m;
      #pragma unroll
      for (int i = 0; i < 8; ++i) {
        bv0[i] = (short)f2b(vg[i * D_HEAD +  0]);
        bv1[i] = (short)f2b(vg[i * D_HEAD + 16]);
        bv2[i] = (short)f2b(vg[i * D_HEAD + 32]);
        bv3[i] = (short)f2b(vg[i * D_HEAD + 48]);
      }
    }
    o0 = __builtin_amdgcn_mfma_f32_16x16x32_bf16(pa, bv0, o0, 0, 0, 0);
    o1 = __builtin_amdgcn_mfma_f32_16x16x32_bf16(pa, bv1, o1, 0, 0, 0);
    o2 = __builtin_amdgcn_mfma_f32_16x16x32_bf16(pa, bv2, o2, 0, 0, 0);
    o3 = __builtin_amdgcn_mfma_f32_16x16x32_bf16(pa, bv3, o3, 0, 0, 0);
  }

  // ---- store O ----
  #pragma unroll
  for (int j = 0; j < 4; ++j) {
    float* op = outp + bhSD + (size_t)(row0 + j) * D_HEAD + m;
    op[ 0] = o0[j];
    op[16] = o1[j];
    op[32] = o2[j];
    op[48] = o3[j];
  }

  // ---- zero-fill cols [32*nC, S) for the tile's 16 rows ----
  const int col0 = nC << 5;
  const int nvec = (S_LEN - col0) >> 2;
  if (nvec > 0) {
    const float4 z = {0.f, 0.f, 0.f, 0.f};
    for (int rl = 0; rl < 16; ++rl) {
      float4* rp = (float4*)(attn + bhSS + (size_t)(q0 + rl) * S_LEN + col0);
      for (int i = lane; i < nvec; i += 64) rp[i] = z;
    }
  }
}

extern "C" void kernel_launch(void* const* d_in, const int* in_sizes, int n_in,
                              void* d_out, int out_size, void* d_ws, size_t ws_size,
                              hipStream_t stream) {
  (void)in_sizes; (void)n_in; (void)out_size;
  const float* q = (const float*)d_in[0];
  const float* k = (const float*)d_in[1];
  const float* v = (const float*)d_in[2];
  float* attn = (float*)d_out;
  float* outp = attn + (size_t)2 * 16 * 2048 * 2048;
  const size_t elems = (size_t)2 * 16 * 2048 * 64;   // 4,194,304 per tensor
  if (ws_size >= elems * 2 * sizeof(unsigned short)) {
    unsigned short* Kb = (unsigned short*)d_ws;
    unsigned short* Vt = Kb + elems;
    convert_kv_kernel<<<4096, 256, 0, stream>>>(k, v, Kb, Vt);
    sdpa_1wave_kernel<true><<<4096, 64, 0, stream>>>(q, k, v, Kb, Vt, attn, outp);
  } else {
    sdpa_1wave_kernel<false><<<4096, 64, 0, stream>>>(q, k, v, nullptr, nullptr, attn, outp);
  }
}

// Round 4
// 196.332 us; speedup vs baseline: 1.5218x; 1.5218x over previous
//
#include <hip/hip_runtime.h>
#include <hip/hip_bf16.h>

// SDPA causal, B=2 H=16 S=2048 D=64, scale=8. Outputs: attn(f32) ++ out(f32).
// R4: R2 structure (strip-paired 256-thr blocks, dbuf LDS) +
//  - K/V pre-converted to bf16, tile-major PRE-SWIZZLED in d_ws (convert kernel)
//  - staging via global_load_lds width=16 (linear LDS dest = swizzled layout)
//  - raw s_barrier + counted vmcnt(16): attn stores stream across barriers
//  - __launch_bounds__(256,4): 4 blocks/CU (40KB LDS each), 16 waves/CU
#define S_LEN 2048
#define D_HEAD 64
#define SD (S_LEN * D_HEAD)      // 131072 elems per bh
#define TILE_B 8192              // 64x64 bf16 tile bytes
#define NTILES 32                // 64-row tiles per bh

typedef __attribute__((ext_vector_type(8))) short short8;   // 8 bf16 MFMA A/B frag
typedef __attribute__((ext_vector_type(4))) float f32x4;    // MFMA C/D frag

__device__ __forceinline__ unsigned short f2b(float f) {    // fp32 -> bf16 (RNE)
  unsigned int u = __float_as_uint(f);
  u += 0x7fffu + ((u >> 16) & 1u);
  return (unsigned short)(u >> 16);
}

__device__ __forceinline__ void gl_lds16(const void* g, void* l) {
  __builtin_amdgcn_global_load_lds(
      (const __attribute__((address_space(1))) unsigned int*)g,
      (__attribute__((address_space(3))) unsigned int*)l, 16, 0, 0);
}

// stage one 8KB tile: 256 thr x 2 insts; LDS linear, source pre-swizzled
__device__ __forceinline__ void stage8k(const char* gsrc, char* ldst, int w, int lane) {
  gl_lds16(gsrc + ((w * 64 + lane) << 4),        ldst + ((w * 64) << 4));
  gl_lds16(gsrc + ((256 + w * 64 + lane) << 4),  ldst + ((256 + w * 64) << 4));
}

// ---- pre-convert: K tiles swizzled ((s*64+d)*2)^((s&7)<<4);
//      V^T tiles swizzled ((d*64+s)*2)^(((d>>2)&7)<<4) ----
__global__ __launch_bounds__(256) void convert_kv_kernel(
    const float* __restrict__ K, const float* __restrict__ V,
    char* __restrict__ Kpre, char* __restrict__ Vpre) {
  const int bid = blockIdx.x;
  const int tid = threadIdx.x;
  if (bid < 1024) {               // K: (bh,tile), direct chunk permute
    const int bh = bid >> 5, tile = bid & 31;
    const float* Kb = K + (size_t)bh * SD + tile * 64 * 64;
    char* out = Kpre + (size_t)bid * TILE_B;
    #pragma unroll
    for (int j = 0; j < 2; ++j) {
      int c = tid + j * 256;                 // dest 16B-chunk index 0..511
      int sl = c >> 3;                       // row
      int d0 = ((c & 7) ^ (sl & 7)) << 3;    // source d-chunk (inverse swizzle)
      const float* src = Kb + sl * 64 + d0;
      float4 a = *(const float4*)src;
      float4 b = *(const float4*)(src + 4);
      short8 o;
      o[0]=(short)f2b(a.x); o[1]=(short)f2b(a.y); o[2]=(short)f2b(a.z); o[3]=(short)f2b(a.w);
      o[4]=(short)f2b(b.x); o[5]=(short)f2b(b.y); o[6]=(short)f2b(b.z); o[7]=(short)f2b(b.w);
      *(short8*)(out + c * 16) = o;
    }
  } else {                        // V: transpose via padded LDS
    __shared__ float Vl[64][65];
    const int vb = bid - 1024;
    const int bh = vb >> 5, tile = vb & 31;
    const float* Vb = V + (size_t)bh * SD + tile * 64 * 64;
    #pragma unroll
    for (int j = 0; j < 4; ++j) {
      int row = (tid >> 4) + j * 16;
      int c4 = (tid & 15) << 2;
      float4 v = *(const float4*)(Vb + row * 64 + c4);
      Vl[row][c4+0] = v.x; Vl[row][c4+1] = v.y; Vl[row][c4+2] = v.z; Vl[row][c4+3] = v.w;
    }
    __syncthreads();
    char* out = Vpre + (size_t)vb * TILE_B;
    #pragma unroll
    for (int j = 0; j < 2; ++j) {
      int c = tid + j * 256;
      int d = c >> 3;
      int s0 = ((c & 7) ^ ((d >> 2) & 7)) << 3;   // inverse swizzle
      short8 o;
      #pragma unroll
      for (int i = 0; i < 8; ++i) o[i] = (short)f2b(Vl[s0 + i][d]);
      *(short8*)(out + c * 16) = o;
    }
  }
}

__global__ __launch_bounds__(256, 4) void sdpa_pre_kernel(
    const float* __restrict__ Qg, const char* __restrict__ Kpre,
    const char* __restrict__ Vpre, float* __restrict__ attn,
    float* __restrict__ outp) {
  const int bh = blockIdx.x & 31;   // bh pinned to XCD (blockIdx%8 stable per bh)
  const int pi = blockIdx.x >> 5;   // 0..15 -> strips qt=pi and qt=31-pi
  const int tid = threadIdx.x, wave = tid >> 6, lane = tid & 63;
  const int g = lane >> 4, m = lane & 15;
  const int swzK = (m & 7) << 4;

  __shared__ __align__(16) unsigned short Kl[2][4096];   // 2 x 8KB
  __shared__ __align__(16) unsigned short Vt[2][4096];   // 2 x 8KB
  __shared__ __align__(16) unsigned short Pl[4][1024];   // 4 x 2KB per-wave P
  char* const PB = (char*)(&Pl[wave][0]);

  const size_t bhSD = (size_t)bh * SD;
  const size_t bhSS = (size_t)bh << 22;
  const char* KpreBH = Kpre + (size_t)bh * NTILES * TILE_B;
  const char* VpreBH = Vpre + (size_t)bh * NTILES * TILE_B;

  int vro[4], vsz[4];
  #pragma unroll
  for (int dc = 0; dc < 4; ++dc) {
    int d = dc * 16 + m;
    vro[dc] = d << 7;
    vsz[dc] = ((d >> 2) & 7) << 4;
  }
  const float SCL = 0.18033688011112042f;   // log2(e)/8

  for (int sidx = 0; sidx < 2; ++sidx) {
    const int qt = sidx ? (31 - pi) : pi;
    const int q0 = qt << 6;
    const int nIt = qt + 1;
    const int qwrow = q0 + wave * 16;
    const int qbase = qwrow + g * 4;

    // ---- Q A-fragments (pre-scaled; exp -> exp2) ----
    short8 aq0, aq1;
    {
      const float* qp = Qg + bhSD + (size_t)(qwrow + m) * D_HEAD + g * 8;
      float4 x0 = *(const float4*)(qp);
      float4 x1 = *(const float4*)(qp + 4);
      float4 y0 = *(const float4*)(qp + 32);
      float4 y1 = *(const float4*)(qp + 36);
      aq0[0]=(short)f2b(x0.x*SCL); aq0[1]=(short)f2b(x0.y*SCL);
      aq0[2]=(short)f2b(x0.z*SCL); aq0[3]=(short)f2b(x0.w*SCL);
      aq0[4]=(short)f2b(x1.x*SCL); aq0[5]=(short)f2b(x1.y*SCL);
      aq0[6]=(short)f2b(x1.z*SCL); aq0[7]=(short)f2b(x1.w*SCL);
      aq1[0]=(short)f2b(y0.x*SCL); aq1[1]=(short)f2b(y0.y*SCL);
      aq1[2]=(short)f2b(y0.z*SCL); aq1[3]=(short)f2b(y0.w*SCL);
      aq1[4]=(short)f2b(y1.x*SCL); aq1[5]=(short)f2b(y1.y*SCL);
      aq1[6]=(short)f2b(y1.z*SCL); aq1[7]=(short)f2b(y1.w*SCL);
    }

    // ================= Phase 1: row sums of exp =================
    float rs0 = 0.f, rs1 = 0.f, rs2 = 0.f, rs3 = 0.f;
    __builtin_amdgcn_s_barrier();                 // phase entry guard
    stage8k(KpreBH, (char*)Kl[0], wave, lane);
    int cur = 0;
    for (int it = 0; it < nIt; ++it) {
      asm volatile("s_waitcnt vmcnt(0)" ::: "memory");
      __builtin_amdgcn_s_barrier();
      __builtin_amdgcn_sched_barrier(0);
      if (it + 1 < nIt)
        stage8k(KpreBH + (size_t)(it + 1) * TILE_B, (char*)Kl[cur ^ 1], wave, lane);
      asm volatile("" ::: "memory");
      const char* KB = (const char*)Kl[cur];
      const int kc = it << 6;
      #pragma unroll
      for (int t = 0; t < 4; ++t) {
        f32x4 acc = {0.f, 0.f, 0.f, 0.f};
        const int rb = (t * 16 + m) << 7;
        short8 b0 = *(const short8*)(KB + ((rb + g * 16) ^ swzK));
        short8 b1 = *(const short8*)(KB + ((rb + 64 + g * 16) ^ swzK));
        acc = __builtin_amdgcn_mfma_f32_16x16x32_bf16(aq0, b0, acc, 0, 0, 0);
        acc = __builtin_amdgcn_mfma_f32_16x16x32_bf16(aq1, b1, acc, 0, 0, 0);
        const int kcol = kc + t * 16 + m;
        rs0 += (kcol <= qbase + 0) ? exp2f(acc[0]) : 0.f;
        rs1 += (kcol <= qbase + 1) ? exp2f(acc[1]) : 0.f;
        rs2 += (kcol <= qbase + 2) ? exp2f(acc[2]) : 0.f;
        rs3 += (kcol <= qbase + 3) ? exp2f(acc[3]) : 0.f;
      }
      cur ^= 1;
    }
    #pragma unroll
    for (int sft = 1; sft < 16; sft <<= 1) {
      rs0 += __shfl_xor(rs0, sft, 64);
      rs1 += __shfl_xor(rs1, sft, 64);
      rs2 += __shfl_xor(rs2, sft, 64);
      rs3 += __shfl_xor(rs3, sft, 64);
    }
    const float ri0 = 1.f / rs0, ri1 = 1.f / rs1, ri2 = 1.f / rs2, ri3 = 1.f / rs3;

    // ================= Phase 2: recompute, write attn, accumulate O =========
    f32x4 o0 = {0.f,0.f,0.f,0.f}, o1 = {0.f,0.f,0.f,0.f};
    f32x4 o2 = {0.f,0.f,0.f,0.f}, o3 = {0.f,0.f,0.f,0.f};
    __builtin_amdgcn_s_barrier();                 // phase entry guard
    stage8k(KpreBH, (char*)Kl[0], wave, lane);
    stage8k(VpreBH, (char*)Vt[0], wave, lane);
    cur = 0;
    for (int it = 0; it < nIt; ++it) {
      if (it == 0) { asm volatile("s_waitcnt vmcnt(0)" ::: "memory"); }
      else         { asm volatile("s_waitcnt vmcnt(16)" ::: "memory"); }
      __builtin_amdgcn_s_barrier();
      __builtin_amdgcn_sched_barrier(0);
      if (it + 1 < nIt) {
        stage8k(KpreBH + (size_t)(it + 1) * TILE_B, (char*)Kl[cur ^ 1], wave, lane);
        stage8k(VpreBH + (size_t)(it + 1) * TILE_B, (char*)Vt[cur ^ 1], wave, lane);
      }
      asm volatile("" ::: "memory");
      const char* KB = (const char*)Kl[cur];
      const char* VB = (const char*)Vt[cur];
      const int kc = it << 6;
      float* arow = attn + bhSS + (size_t)qbase * S_LEN + kc;
      #pragma unroll
      for (int t = 0; t < 4; ++t) {
        f32x4 acc = {0.f, 0.f, 0.f, 0.f};
        const int rb = (t * 16 + m) << 7;
        short8 b0 = *(const short8*)(KB + ((rb + g * 16) ^ swzK));
        short8 b1 = *(const short8*)(KB + ((rb + 64 + g * 16) ^ swzK));
        acc = __builtin_amdgcn_mfma_f32_16x16x32_bf16(aq0, b0, acc, 0, 0, 0);
        acc = __builtin_amdgcn_mfma_f32_16x16x32_bf16(aq1, b1, acc, 0, 0, 0);
        const int kcol = kc + t * 16 + m;
        const int tc = t * 16 + m;
        float p0 = (kcol <= qbase + 0) ? exp2f(acc[0]) * ri0 : 0.f;
        float p1 = (kcol <= qbase + 1) ? exp2f(acc[1]) * ri1 : 0.f;
        float p2 = (kcol <= qbase + 2) ? exp2f(acc[2]) * ri2 : 0.f;
        float p3 = (kcol <= qbase + 3) ? exp2f(acc[3]) * ri3 : 0.f;
        arow[0 * S_LEN + tc] = p0;
        arow[1 * S_LEN + tc] = p1;
        arow[2 * S_LEN + tc] = p2;
        arow[3 * S_LEN + tc] = p3;
        const int r0 = g * 4, c2 = tc << 1;
        *(unsigned short*)(PB + ((((r0+0)<<7) + c2) ^ (((r0+0)&7)<<4))) = f2b(p0);
        *(unsigned short*)(PB + ((((r0+1)<<7) + c2) ^ (((r0+1)&7)<<4))) = f2b(p1);
        *(unsigned short*)(PB + ((((r0+2)<<7) + c2) ^ (((r0+2)&7)<<4))) = f2b(p2);
        *(unsigned short*)(PB + ((((r0+3)<<7) + c2) ^ (((r0+3)&7)<<4))) = f2b(p3);
      }
      // PV: A = P rows (row=m), B = V^T (row=d)
      short8 pa0 = *(const short8*)(PB + (((m << 7) + g * 16) ^ swzK));
      short8 pa1 = *(const short8*)(PB + (((m << 7) + 64 + g * 16) ^ swzK));
      #pragma unroll
      for (int dc = 0; dc < 4; ++dc) {
        short8 bv0 = *(const short8*)(VB + ((vro[dc] + g * 16) ^ vsz[dc]));
        short8 bv1 = *(const short8*)(VB + ((vro[dc] + 64 + g * 16) ^ vsz[dc]));
        f32x4& od = (dc == 0) ? o0 : (dc == 1) ? o1 : (dc == 2) ? o2 : o3;
        od = __builtin_amdgcn_mfma_f32_16x16x32_bf16(pa0, bv0, od, 0, 0, 0);
        od = __builtin_amdgcn_mfma_f32_16x16x32_bf16(pa1, bv1, od, 0, 0, 0);
      }
      cur ^= 1;
    }

    // ---- store O ----
    #pragma unroll
    for (int reg = 0; reg < 4; ++reg) {
      float* op = outp + bhSD + (size_t)(qbase + reg) * D_HEAD + m;
      op[ 0] = o0[reg];
      op[16] = o1[reg];
      op[32] = o2[reg];
      op[48] = o3[reg];
    }

    // ---- zero-fill cols [kmax, S) for this strip's 64 rows ----
    const int col0 = nIt << 6;
    const int nvec = (S_LEN - col0) >> 2;
    if (nvec > 0) {
      const float4 z = {0.f, 0.f, 0.f, 0.f};
      for (int r = 0; r < 64; ++r) {
        float4* rp = (float4*)(attn + bhSS + (size_t)(q0 + r) * S_LEN + col0);
        for (int i = tid; i < nvec; i += 256) rp[i] = z;
      }
    }
  }
}

// ================== fallback (ws too small): R2 kernel verbatim ==================
__global__ __launch_bounds__(256) void sdpa_fb_kernel(
    const float* __restrict__ Qg, const float* __restrict__ Kg,
    const float* __restrict__ Vg, float* __restrict__ attn,
    float* __restrict__ outp) {
  const int bh = blockIdx.x >> 4;
  const int pi = blockIdx.x & 15;
  const int tid  = threadIdx.x;
  const int wave = tid >> 6;
  const int lane = tid & 63;
  const int g = lane >> 4;
  const int m = lane & 15;
  const int swzK = (m & 7) << 4;
  __shared__ __align__(16) unsigned short Kl[2][64 * 64];
  __shared__ __align__(16) unsigned short Vt[2][64 * 64];
  __shared__ __align__(16) unsigned short Pl[4][16 * 64];
  char* const PB = (char*)(&Pl[wave][0]);
  const size_t bhSD = (size_t)bh * (S_LEN * D_HEAD);
  const size_t bhSS = (size_t)bh * ((size_t)S_LEN * S_LEN);
  int ss[4], dd[4], koff[4];
  #pragma unroll
  for (int j = 0; j < 4; ++j) {
    int f = tid + j * 256;
    ss[j] = f >> 4;
    dd[j] = (f & 15) << 2;
    koff[j] = (((ss[j] << 6) + dd[j]) << 1) ^ ((ss[j] & 7) << 4);
  }
  int vro[4], vsz[4];
  #pragma unroll
  for (int dc = 0; dc < 4; ++dc) {
    int d = dc * 16 + m;
    vro[dc] = d << 7;
    vsz[dc] = ((d >> 2) & 7) << 4;
  }
  const float SCL = 0.18033688011112042f;
  for (int sidx = 0; sidx < 2; ++sidx) {
    const int qt = sidx ? (31 - pi) : pi;
    const int q0 = qt << 6;
    const int kmax = q0 + 64;
    const int nIter = kmax >> 6;
    const int qwrow = q0 + wave * 16;
    const int qbase = qwrow + g * 4;
    short8 aq0, aq1;
    {
      const float* qp = Qg + bhSD + (size_t)(qwrow + m) * D_HEAD + g * 8;
      float4 x0 = *(const float4*)(qp);
      float4 x1 = *(const float4*)(qp + 4);
      float4 y0 = *(const float4*)(qp + 32);
      float4 y1 = *(const float4*)(qp + 36);
      aq0[0]=(short)f2b(x0.x*SCL); aq0[1]=(short)f2b(x0.y*SCL);
      aq0[2]=(short)f2b(x0.z*SCL); aq0[3]=(short)f2b(x0.w*SCL);
      aq0[4]=(short)f2b(x1.x*SCL); aq0[5]=(short)f2b(x1.y*SCL);
      aq0[6]=(short)f2b(x1.z*SCL); aq0[7]=(short)f2b(x1.w*SCL);
      aq1[0]=(short)f2b(y0.x*SCL); aq1[1]=(short)f2b(y0.y*SCL);
      aq1[2]=(short)f2b(y0.z*SCL); aq1[3]=(short)f2b(y0.w*SCL);
      aq1[4]=(short)f2b(y1.x*SCL); aq1[5]=(short)f2b(y1.y*SCL);
      aq1[6]=(short)f2b(y1.z*SCL); aq1[7]=(short)f2b(y1.w*SCL);
    }
    float rs0 = 0.f, rs1 = 0.f, rs2 = 0.f, rs3 = 0.f;
    {
      float4 kr[4];
      #pragma unroll
      for (int j = 0; j < 4; ++j)
        kr[j] = *(const float4*)(Kg + bhSD + (size_t)ss[j] * D_HEAD + dd[j]);
      #pragma unroll
      for (int j = 0; j < 4; ++j) {
        ushort4 kb;
        kb.x = f2b(kr[j].x); kb.y = f2b(kr[j].y);
        kb.z = f2b(kr[j].z); kb.w = f2b(kr[j].w);
        *(ushort4*)((char*)Kl[0] + koff[j]) = kb;
      }
    }
    __syncthreads();
    int cur = 0;
    for (int it = 0; it < nIter; ++it) {
      const int kc = it << 6;
      const bool pf = (it + 1 < nIter);
      float4 kr[4];
      if (pf) {
        #pragma unroll
        for (int j = 0; j < 4; ++j)
          kr[j] = *(const float4*)(Kg + bhSD + (size_t)(kc + 64 + ss[j]) * D_HEAD + dd[j]);
      }
      const char* KB = (const char*)Kl[cur];
      #pragma unroll
      for (int t = 0; t < 4; ++t) {
        f32x4 acc = {0.f, 0.f, 0.f, 0.f};
        const int rb = (t * 16 + m) << 7;
        short8 b0 = *(const short8*)(KB + ((rb + g * 16) ^ swzK));
        short8 b1 = *(const short8*)(KB + ((rb + 64 + g * 16) ^ swzK));
        acc = __builtin_amdgcn_mfma_f32_16x16x32_bf16(aq0, b0, acc, 0, 0, 0);
        acc = __builtin_amdgcn_mfma_f32_16x16x32_bf16(aq1, b1, acc, 0, 0, 0);
        const int kcol = kc + t * 16 + m;
        rs0 += (kcol <= qbase + 0) ? exp2f(acc[0]) : 0.f;
        rs1 += (kcol <= qbase + 1) ? exp2f(acc[1]) : 0.f;
        rs2 += (kcol <= qbase + 2) ? exp2f(acc[2]) : 0.f;
        rs3 += (kcol <= qbase + 3) ? exp2f(acc[3]) : 0.f;
      }
      if (pf) {
        #pragma unroll
        for (int j = 0; j < 4; ++j) {
          ushort4 kb;
          kb.x = f2b(kr[j].x); kb.y = f2b(kr[j].y);
          kb.z = f2b(kr[j].z); kb.w = f2b(kr[j].w);
          *(ushort4*)((char*)Kl[cur ^ 1] + koff[j]) = kb;
        }
      }
      __syncthreads();
      cur ^= 1;
    }
    #pragma unroll
    for (int sft = 1; sft < 16; sft <<= 1) {
      rs0 += __shfl_xor(rs0, sft, 64);
      rs1 += __shfl_xor(rs1, sft, 64);
      rs2 += __shfl_xor(rs2, sft, 64);
      rs3 += __shfl_xor(rs3, sft, 64);
    }
    const float ri0 = 1.f / rs0, ri1 = 1.f / rs1, ri2 = 1.f / rs2, ri3 = 1.f / rs3;
    f32x4 o0 = {0.f,0.f,0.f,0.f}, o1 = {0.f,0.f,0.f,0.f};
    f32x4 o2 = {0.f,0.f,0.f,0.f}, o3 = {0.f,0.f,0.f,0.f};
    {
      float4 kr[4], vr[4];
      #pragma unroll
      for (int j = 0; j < 4; ++j) {
        kr[j] = *(const float4*)(Kg + bhSD + (size_t)ss[j] * D_HEAD + dd[j]);
        vr[j] = *(const float4*)(Vg + bhSD + (size_t)ss[j] * D_HEAD + dd[j]);
      }
      #pragma unroll
      for (int j = 0; j < 4; ++j) {
        ushort4 kb;
        kb.x = f2b(kr[j].x); kb.y = f2b(kr[j].y);
        kb.z = f2b(kr[j].z); kb.w = f2b(kr[j].w);
        *(ushort4*)((char*)Kl[0] + koff[j]) = kb;
        const int d0 = dd[j], s2 = ss[j] << 1;
        char* VB1 = (char*)Vt[0];
        *(unsigned short*)(VB1 + ((((d0+0)<<7) + s2) ^ ((((d0+0)>>2)&7)<<4))) = f2b(vr[j].x);
        *(unsigned short*)(VB1 + ((((d0+1)<<7) + s2) ^ ((((d0+1)>>2)&7)<<4))) = f2b(vr[j].y);
        *(unsigned short*)(VB1 + ((((d0+2)<<7) + s2) ^ ((((d0+2)>>2)&7)<<4))) = f2b(vr[j].z);
        *(unsigned short*)(VB1 + ((((d0+3)<<7) + s2) ^ ((((d0+3)>>2)&7)<<4))) = f2b(vr[j].w);
      }
    }
    __syncthreads();
    cur = 0;
    for (int it = 0; it < nIter; ++it) {
      const int kc = it << 6;
      const bool pf = (it + 1 < nIter);
      float4 kr[4], vr[4];
      if (pf) {
        #pragma unroll
        for (int j = 0; j < 4; ++j) {
          kr[j] = *(const float4*)(Kg + bhSD + (size_t)(kc + 64 + ss[j]) * D_HEAD + dd[j]);
          vr[j] = *(const float4*)(Vg + bhSD + (size_t)(kc + 64 + ss[j]) * D_HEAD + dd[j]);
        }
      }
      const char* KB = (const char*)Kl[cur];
      const char* VB = (const char*)Vt[cur];
      float* arow = attn + bhSS + (size_t)qbase * S_LEN + kc;
      #pragma unroll
      for (int t = 0; t < 4; ++t) {
        f32x4 acc = {0.f, 0.f, 0.f, 0.f};
        const int rb = (t * 16 + m) << 7;
        short8 b0 = *(const short8*)(KB + ((rb + g * 16) ^ swzK));
        short8 b1 = *(const short8*)(KB + ((rb + 64 + g * 16) ^ swzK));
        acc = __builtin_amdgcn_mfma_f32_16x16x32_bf16(aq0, b0, acc, 0, 0, 0);
        acc = __builtin_amdgcn_mfma_f32_16x16x32_bf16(aq1, b1, acc, 0, 0, 0);
        const int kcol = kc + t * 16 + m;
        const int tc = t * 16 + m;
        float p0 = (kcol <= qbase + 0) ? exp2f(acc[0]) * ri0 : 0.f;
        float p1 = (kcol <= qbase + 1) ? exp2f(acc[1]) * ri1 : 0.f;
        float p2 = (kcol <= qbase + 2) ? exp2f(acc[2]) * ri2 : 0.f;
        float p3 = (kcol <= qbase + 3) ? exp2f(acc[3]) * ri3 : 0.f;
        arow[0 * S_LEN + tc] = p0;
        arow[1 * S_LEN + tc] = p1;
        arow[2 * S_LEN + tc] = p2;
        arow[3 * S_LEN + tc] = p3;
        const int r0 = g * 4, c2 = tc << 1;
        *(unsigned short*)(PB + ((((r0+0)<<7) + c2) ^ (((r0+0)&7)<<4))) = f2b(p0);
        *(unsigned short*)(PB + ((((r0+1)<<7) + c2) ^ (((r0+1)&7)<<4))) = f2b(p1);
        *(unsigned short*)(PB + ((((r0+2)<<7) + c2) ^ (((r0+2)&7)<<4))) = f2b(p2);
        *(unsigned short*)(PB + ((((r0+3)<<7) + c2) ^ (((r0+3)&7)<<4))) = f2b(p3);
      }
      short8 pa0 = *(const short8*)(PB + (((m << 7) + g * 16) ^ swzK));
      short8 pa1 = *(const short8*)(PB + (((m << 7) + 64 + g * 16) ^ swzK));
      #pragma unroll
      for (int dc = 0; dc < 4; ++dc) {
        short8 bv0 = *(const short8*)(VB + ((vro[dc] + g * 16) ^ vsz[dc]));
        short8 bv1 = *(const short8*)(VB + ((vro[dc] + 64 + g * 16) ^ vsz[dc]));
        f32x4& od = (dc == 0) ? o0 : (dc == 1) ? o1 : (dc == 2) ? o2 : o3;
        od = __builtin_amdgcn_mfma_f32_16x16x32_bf16(pa0, bv0, od, 0, 0, 0);
        od = __builtin_amdgcn_mfma_f32_16x16x32_bf16(pa1, bv1, od, 0, 0, 0);
      }
      if (pf) {
        #pragma unroll
        for (int j = 0; j < 4; ++j) {
          ushort4 kb;
          kb.x = f2b(kr[j].x); kb.y = f2b(kr[j].y);
          kb.z = f2b(kr[j].z); kb.w = f2b(kr[j].w);
          *(ushort4*)((char*)Kl[cur ^ 1] + koff[j]) = kb;
          const int d0 = dd[j], s2 = ss[j] << 1;
          char* VB1 = (char*)Vt[cur ^ 1];
          *(unsigned short*)(VB1 + ((((d0+0)<<7) + s2) ^ ((((d0+0)>>2)&7)<<4))) = f2b(vr[j].x);
          *(unsigned short*)(VB1 + ((((d0+1)<<7) + s2) ^ ((((d0+1)>>2)&7)<<4))) = f2b(vr[j].y);
          *(unsigned short*)(VB1 + ((((d0+2)<<7) + s2) ^ ((((d0+2)>>2)&7)<<4))) = f2b(vr[j].z);
          *(unsigned short*)(VB1 + ((((d0+3)<<7) + s2) ^ ((((d0+3)>>2)&7)<<4))) = f2b(vr[j].w);
        }
      }
      __syncthreads();
      cur ^= 1;
    }
    #pragma unroll
    for (int reg = 0; reg < 4; ++reg) {
      float* op = outp + bhSD + (size_t)(qbase + reg) * D_HEAD + m;
      op[ 0] = o0[reg];
      op[16] = o1[reg];
      op[32] = o2[reg];
      op[48] = o3[reg];
    }
    const int ncols = S_LEN - kmax;
    if (ncols > 0) {
      const float4 z = {0.f, 0.f, 0.f, 0.f};
      const int nvec = ncols >> 2;
      for (int r = 0; r < 64; ++r) {
        float4* rp = (float4*)(attn + bhSS + (size_t)(q0 + r) * S_LEN + kmax);
        for (int i = tid; i < nvec; i += 256) rp[i] = z;
      }
    }
  }
}

extern "C" void kernel_launch(void* const* d_in, const int* in_sizes, int n_in,
                              void* d_out, int out_size, void* d_ws, size_t ws_size,
                              hipStream_t stream) {
  (void)in_sizes; (void)n_in; (void)out_size;
  const float* q = (const float*)d_in[0];
  const float* k = (const float*)d_in[1];
  const float* v = (const float*)d_in[2];
  float* attn = (float*)d_out;
  float* outp = attn + (size_t)2 * 16 * 2048 * 2048;
  const size_t pre_bytes = (size_t)32 * NTILES * TILE_B;   // 8.39 MB per tensor
  if (ws_size >= 2 * pre_bytes) {
    char* Kpre = (char*)d_ws;
    char* Vpre = Kpre + pre_bytes;
    convert_kv_kernel<<<2048, 256, 0, stream>>>(k, v, Kpre, Vpre);
    sdpa_pre_kernel<<<512, 256, 0, stream>>>(q, Kpre, Vpre, attn, outp);
  } else {
    sdpa_fb_kernel<<<512, 256, 0, stream>>>(q, k, v, attn, outp);
  }
}

// Round 5
// 179.799 us; speedup vs baseline: 1.6617x; 1.0920x over previous
//
#include <hip/hip_runtime.h>
#include <hip/hip_bf16.h>

// SDPA causal, B=2 H=16 S=2048 D=64, scale=8. Outputs: attn(f32) ++ out(f32).
// R5: R4 + grid 1024 (1 strip/block, CU-quad-balanced mapping, 4 blocks/CU =
// 16 waves/CU) + attn stores via P-LDS as dwordx4 (float(bf16)) with vmcnt(4).
#define S_LEN 2048
#define D_HEAD 64
#define SD (S_LEN * D_HEAD)      // 131072 elems per bh
#define TILE_B 8192              // 64x64 bf16 tile bytes
#define NTILES 32                // 64-row tiles per bh

typedef __attribute__((ext_vector_type(8))) short short8;   // 8 bf16 MFMA A/B frag
typedef __attribute__((ext_vector_type(4))) float f32x4;    // MFMA C/D frag

__device__ __forceinline__ unsigned short f2b(float f) {    // fp32 -> bf16 (RNE)
  unsigned int u = __float_as_uint(f);
  u += 0x7fffu + ((u >> 16) & 1u);
  return (unsigned short)(u >> 16);
}

__device__ __forceinline__ float b2f(unsigned short s) {
  return __uint_as_float(((unsigned int)s) << 16);
}

__device__ __forceinline__ void gl_lds16(const void* g, void* l) {
  __builtin_amdgcn_global_load_lds(
      (const __attribute__((address_space(1))) unsigned int*)g,
      (__attribute__((address_space(3))) unsigned int*)l, 16, 0, 0);
}

// stage one 8KB tile: 256 thr x 2 insts; LDS linear, source pre-swizzled
__device__ __forceinline__ void stage8k(const char* gsrc, char* ldst, int w, int lane) {
  gl_lds16(gsrc + ((w * 64 + lane) << 4),        ldst + ((w * 64) << 4));
  gl_lds16(gsrc + ((256 + w * 64 + lane) << 4),  ldst + ((256 + w * 64) << 4));
}

// ---- pre-convert: K tiles swizzled ((s*64+d)*2)^((s&7)<<4);
//      V^T tiles swizzled ((d*64+s)*2)^(((d>>2)&7)<<4) ----
__global__ __launch_bounds__(256) void convert_kv_kernel(
    const float* __restrict__ K, const float* __restrict__ V,
    char* __restrict__ Kpre, char* __restrict__ Vpre) {
  const int bid = blockIdx.x;
  const int tid = threadIdx.x;
  if (bid < 1024) {               // K: (bh,tile), direct chunk permute
    const int bh = bid >> 5, tile = bid & 31;
    const float* Kb = K + (size_t)bh * SD + tile * 64 * 64;
    char* out = Kpre + (size_t)bid * TILE_B;
    #pragma unroll
    for (int j = 0; j < 2; ++j) {
      int c = tid + j * 256;                 // dest 16B-chunk index 0..511
      int sl = c >> 3;                       // row
      int d0 = ((c & 7) ^ (sl & 7)) << 3;    // source d-chunk (inverse swizzle)
      const float* src = Kb + sl * 64 + d0;
      float4 a = *(const float4*)src;
      float4 b = *(const float4*)(src + 4);
      short8 o;
      o[0]=(short)f2b(a.x); o[1]=(short)f2b(a.y); o[2]=(short)f2b(a.z); o[3]=(short)f2b(a.w);
      o[4]=(short)f2b(b.x); o[5]=(short)f2b(b.y); o[6]=(short)f2b(b.z); o[7]=(short)f2b(b.w);
      *(short8*)(out + c * 16) = o;
    }
  } else {                        // V: transpose via padded LDS
    __shared__ float Vl[64][65];
    const int vb = bid - 1024;
    const int bh = vb >> 5, tile = vb & 31;
    const float* Vb = V + (size_t)bh * SD + tile * 64 * 64;
    #pragma unroll
    for (int j = 0; j < 4; ++j) {
      int row = (tid >> 4) + j * 16;
      int c4 = (tid & 15) << 2;
      float4 v = *(const float4*)(Vb + row * 64 + c4);
      Vl[row][c4+0] = v.x; Vl[row][c4+1] = v.y; Vl[row][c4+2] = v.z; Vl[row][c4+3] = v.w;
    }
    __syncthreads();
    char* out = Vpre + (size_t)vb * TILE_B;
    #pragma unroll
    for (int j = 0; j < 2; ++j) {
      int c = tid + j * 256;
      int d = c >> 3;
      int s0 = ((c & 7) ^ ((d >> 2) & 7)) << 3;   // inverse swizzle
      short8 o;
      #pragma unroll
      for (int i = 0; i < 8; ++i) o[i] = (short)f2b(Vl[s0 + i][d]);
      *(short8*)(out + c * 16) = o;
    }
  }
}

__global__ __launch_bounds__(256, 4) void sdpa_pre_kernel(
    const float* __restrict__ Qg, const char* __restrict__ Kpre,
    const char* __restrict__ Vpre, float* __restrict__ attn,
    float* __restrict__ outp) {
  // CU-quad-balanced mapping (assumes round-robin dispatch, XCD = b%8, m09):
  // quad {b, b+256, b+512, b+768} -> same CU, same bh, qt set {u,15-u,16+u,31-u}
  const int j  = blockIdx.x >> 8;          // 0..3
  const int rr = blockIdx.x & 255;
  const int xcd = rr & 7;
  const int cu  = rr >> 3;                 // 0..31
  const int bh  = xcd + ((cu & 3) << 3);   // 0..31, pinned to XCD
  const int u   = cu >> 2;                 // 0..7
  const int qt  = (j == 0) ? u : (j == 1) ? (15 - u) : (j == 2) ? (16 + u) : (31 - u);

  const int tid = threadIdx.x, wave = tid >> 6, lane = tid & 63;
  const int g = lane >> 4, m = lane & 15;
  const int swzK = (m & 7) << 4;

  __shared__ __align__(16) unsigned short Kl[2][4096];   // 2 x 8KB
  __shared__ __align__(16) unsigned short Vt[2][4096];   // 2 x 8KB
  __shared__ __align__(16) unsigned short Pl[4][1024];   // 4 x 2KB per-wave P
  char* const PB = (char*)(&Pl[wave][0]);

  const size_t bhSD = (size_t)bh * SD;
  const size_t bhSS = (size_t)bh << 22;
  const char* KpreBH = Kpre + (size_t)bh * NTILES * TILE_B;
  const char* VpreBH = Vpre + (size_t)bh * NTILES * TILE_B;

  int vro[4], vsz[4];
  #pragma unroll
  for (int dc = 0; dc < 4; ++dc) {
    int d = dc * 16 + m;
    vro[dc] = d << 7;
    vsz[dc] = ((d >> 2) & 7) << 4;
  }
  const float SCL = 0.18033688011112042f;   // log2(e)/8

  const int q0 = qt << 6;
  const int nIt = qt + 1;
  const int qwrow = q0 + wave * 16;
  const int qbase = qwrow + g * 4;

  // ---- Q A-fragments (pre-scaled; exp -> exp2) ----
  short8 aq0, aq1;
  {
    const float* qp = Qg + bhSD + (size_t)(qwrow + m) * D_HEAD + g * 8;
    float4 x0 = *(const float4*)(qp);
    float4 x1 = *(const float4*)(qp + 4);
    float4 y0 = *(const float4*)(qp + 32);
    float4 y1 = *(const float4*)(qp + 36);
    aq0[0]=(short)f2b(x0.x*SCL); aq0[1]=(short)f2b(x0.y*SCL);
    aq0[2]=(short)f2b(x0.z*SCL); aq0[3]=(short)f2b(x0.w*SCL);
    aq0[4]=(short)f2b(x1.x*SCL); aq0[5]=(short)f2b(x1.y*SCL);
    aq0[6]=(short)f2b(x1.z*SCL); aq0[7]=(short)f2b(x1.w*SCL);
    aq1[0]=(short)f2b(y0.x*SCL); aq1[1]=(short)f2b(y0.y*SCL);
    aq1[2]=(short)f2b(y0.z*SCL); aq1[3]=(short)f2b(y0.w*SCL);
    aq1[4]=(short)f2b(y1.x*SCL); aq1[5]=(short)f2b(y1.y*SCL);
    aq1[6]=(short)f2b(y1.z*SCL); aq1[7]=(short)f2b(y1.w*SCL);
  }

  // ================= Phase 1: row sums of exp =================
  float rs0 = 0.f, rs1 = 0.f, rs2 = 0.f, rs3 = 0.f;
  __builtin_amdgcn_s_barrier();
  stage8k(KpreBH, (char*)Kl[0], wave, lane);
  int cur = 0;
  for (int it = 0; it < nIt; ++it) {
    asm volatile("s_waitcnt vmcnt(0)" ::: "memory");
    __builtin_amdgcn_s_barrier();
    __builtin_amdgcn_sched_barrier(0);
    if (it + 1 < nIt)
      stage8k(KpreBH + (size_t)(it + 1) * TILE_B, (char*)Kl[cur ^ 1], wave, lane);
    asm volatile("" ::: "memory");
    const char* KB = (const char*)Kl[cur];
    const int kc = it << 6;
    #pragma unroll
    for (int t = 0; t < 4; ++t) {
      f32x4 acc = {0.f, 0.f, 0.f, 0.f};
      const int rb = (t * 16 + m) << 7;
      short8 b0 = *(const short8*)(KB + ((rb + g * 16) ^ swzK));
      short8 b1 = *(const short8*)(KB + ((rb + 64 + g * 16) ^ swzK));
      acc = __builtin_amdgcn_mfma_f32_16x16x32_bf16(aq0, b0, acc, 0, 0, 0);
      acc = __builtin_amdgcn_mfma_f32_16x16x32_bf16(aq1, b1, acc, 0, 0, 0);
      const int kcol = kc + t * 16 + m;
      rs0 += (kcol <= qbase + 0) ? exp2f(acc[0]) : 0.f;
      rs1 += (kcol <= qbase + 1) ? exp2f(acc[1]) : 0.f;
      rs2 += (kcol <= qbase + 2) ? exp2f(acc[2]) : 0.f;
      rs3 += (kcol <= qbase + 3) ? exp2f(acc[3]) : 0.f;
    }
    cur ^= 1;
  }
  #pragma unroll
  for (int sft = 1; sft < 16; sft <<= 1) {
    rs0 += __shfl_xor(rs0, sft, 64);
    rs1 += __shfl_xor(rs1, sft, 64);
    rs2 += __shfl_xor(rs2, sft, 64);
    rs3 += __shfl_xor(rs3, sft, 64);
  }
  const float ri0 = 1.f / rs0, ri1 = 1.f / rs1, ri2 = 1.f / rs2, ri3 = 1.f / rs3;

  // ================= Phase 2: recompute, write attn, accumulate O =========
  f32x4 o0 = {0.f,0.f,0.f,0.f}, o1 = {0.f,0.f,0.f,0.f};
  f32x4 o2 = {0.f,0.f,0.f,0.f}, o3 = {0.f,0.f,0.f,0.f};
  __builtin_amdgcn_s_barrier();
  stage8k(KpreBH, (char*)Kl[0], wave, lane);
  stage8k(VpreBH, (char*)Vt[0], wave, lane);
  cur = 0;
  const int sr = lane >> 2;     // attn-store row (0..15)
  const int cq = lane & 3;      // attn-store col quarter
  for (int it = 0; it < nIt; ++it) {
    if (it == 0) { asm volatile("s_waitcnt vmcnt(0)" ::: "memory"); }
    else         { asm volatile("s_waitcnt vmcnt(4)" ::: "memory"); }
    __builtin_amdgcn_s_barrier();
    __builtin_amdgcn_sched_barrier(0);
    if (it + 1 < nIt) {                       // 4 vm loads, FIRST vm ops of iter
      stage8k(KpreBH + (size_t)(it + 1) * TILE_B, (char*)Kl[cur ^ 1], wave, lane);
      stage8k(VpreBH + (size_t)(it + 1) * TILE_B, (char*)Vt[cur ^ 1], wave, lane);
    }
    asm volatile("" ::: "memory");
    const char* KB = (const char*)Kl[cur];
    const char* VB = (const char*)Vt[cur];
    const int kc = it << 6;
    #pragma unroll
    for (int t = 0; t < 4; ++t) {
      f32x4 acc = {0.f, 0.f, 0.f, 0.f};
      const int rb = (t * 16 + m) << 7;
      short8 b0 = *(const short8*)(KB + ((rb + g * 16) ^ swzK));
      short8 b1 = *(const short8*)(KB + ((rb + 64 + g * 16) ^ swzK));
      acc = __builtin_amdgcn_mfma_f32_16x16x32_bf16(aq0, b0, acc, 0, 0, 0);
      acc = __builtin_amdgcn_mfma_f32_16x16x32_bf16(aq1, b1, acc, 0, 0, 0);
      const int kcol = kc + t * 16 + m;
      const int tc = t * 16 + m;
      float p0 = (kcol <= qbase + 0) ? exp2f(acc[0]) * ri0 : 0.f;
      float p1 = (kcol <= qbase + 1) ? exp2f(acc[1]) * ri1 : 0.f;
      float p2 = (kcol <= qbase + 2) ? exp2f(acc[2]) * ri2 : 0.f;
      float p3 = (kcol <= qbase + 3) ? exp2f(acc[3]) * ri3 : 0.f;
      const int r0 = g * 4, c2 = tc << 1;
      *(unsigned short*)(PB + ((((r0+0)<<7) + c2) ^ (((r0+0)&7)<<4))) = f2b(p0);
      *(unsigned short*)(PB + ((((r0+1)<<7) + c2) ^ (((r0+1)&7)<<4))) = f2b(p1);
      *(unsigned short*)(PB + ((((r0+2)<<7) + c2) ^ (((r0+2)&7)<<4))) = f2b(p2);
      *(unsigned short*)(PB + ((((r0+3)<<7) + c2) ^ (((r0+3)&7)<<4))) = f2b(p3);
    }
    // attn f32 stores from P-LDS: lane -> row sr, cols [16cq+8h, +8); 4 dwordx4
    {
      float* arow = attn + bhSS + (size_t)(qwrow + sr) * S_LEN + kc + cq * 16;
      #pragma unroll
      for (int h = 0; h < 2; ++h) {
        const int off = (((sr << 7) + (cq << 5) + (h << 4))) ^ ((sr & 7) << 4);
        short8 pr = *(const short8*)(PB + off);
        float4 fa, fb;
        fa.x = b2f((unsigned short)pr[0]); fa.y = b2f((unsigned short)pr[1]);
        fa.z = b2f((unsigned short)pr[2]); fa.w = b2f((unsigned short)pr[3]);
        fb.x = b2f((unsigned short)pr[4]); fb.y = b2f((unsigned short)pr[5]);
        fb.z = b2f((unsigned short)pr[6]); fb.w = b2f((unsigned short)pr[7]);
        *(float4*)(arow + 8 * h)     = fa;
        *(float4*)(arow + 8 * h + 4) = fb;
      }
    }
    // PV: A = P rows (row=m), B = V^T (row=d)
    short8 pa0 = *(const short8*)(PB + (((m << 7) + g * 16) ^ swzK));
    short8 pa1 = *(const short8*)(PB + (((m << 7) + 64 + g * 16) ^ swzK));
    #pragma unroll
    for (int dc = 0; dc < 4; ++dc) {
      short8 bv0 = *(const short8*)(VB + ((vro[dc] + g * 16) ^ vsz[dc]));
      short8 bv1 = *(const short8*)(VB + ((vro[dc] + 64 + g * 16) ^ vsz[dc]));
      f32x4& od = (dc == 0) ? o0 : (dc == 1) ? o1 : (dc == 2) ? o2 : o3;
      od = __builtin_amdgcn_mfma_f32_16x16x32_bf16(pa0, bv0, od, 0, 0, 0);
      od = __builtin_amdgcn_mfma_f32_16x16x32_bf16(pa1, bv1, od, 0, 0, 0);
    }
    cur ^= 1;
  }

  // ---- store O ----
  #pragma unroll
  for (int reg = 0; reg < 4; ++reg) {
    float* op = outp + bhSD + (size_t)(qbase + reg) * D_HEAD + m;
    op[ 0] = o0[reg];
    op[16] = o1[reg];
    op[32] = o2[reg];
    op[48] = o3[reg];
  }

  // ---- zero-fill cols [kmax, S) for this strip's 64 rows ----
  const int col0 = nIt << 6;
  const int nvec = (S_LEN - col0) >> 2;
  if (nvec > 0) {
    const float4 z = {0.f, 0.f, 0.f, 0.f};
    for (int r = 0; r < 64; ++r) {
      float4* rp = (float4*)(attn + bhSS + (size_t)(q0 + r) * S_LEN + col0);
      for (int i = tid; i < nvec; i += 256) rp[i] = z;
    }
  }
}

// ================== fallback (ws too small): R2 kernel verbatim ==================
__global__ __launch_bounds__(256) void sdpa_fb_kernel(
    const float* __restrict__ Qg, const float* __restrict__ Kg,
    const float* __restrict__ Vg, float* __restrict__ attn,
    float* __restrict__ outp) {
  const int bh = blockIdx.x >> 4;
  const int pi = blockIdx.x & 15;
  const int tid  = threadIdx.x;
  const int wave = tid >> 6;
  const int lane = tid & 63;
  const int g = lane >> 4;
  const int m = lane & 15;
  const int swzK = (m & 7) << 4;
  __shared__ __align__(16) unsigned short Kl[2][64 * 64];
  __shared__ __align__(16) unsigned short Vt[2][64 * 64];
  __shared__ __align__(16) unsigned short Pl[4][16 * 64];
  char* const PB = (char*)(&Pl[wave][0]);
  const size_t bhSD = (size_t)bh * (S_LEN * D_HEAD);
  const size_t bhSS = (size_t)bh * ((size_t)S_LEN * S_LEN);
  int ss[4], dd[4], koff[4];
  #pragma unroll
  for (int j = 0; j < 4; ++j) {
    int f = tid + j * 256;
    ss[j] = f >> 4;
    dd[j] = (f & 15) << 2;
    koff[j] = (((ss[j] << 6) + dd[j]) << 1) ^ ((ss[j] & 7) << 4);
  }
  int vro[4], vsz[4];
  #pragma unroll
  for (int dc = 0; dc < 4; ++dc) {
    int d = dc * 16 + m;
    vro[dc] = d << 7;
    vsz[dc] = ((d >> 2) & 7) << 4;
  }
  const float SCL = 0.18033688011112042f;
  for (int sidx = 0; sidx < 2; ++sidx) {
    const int qt = sidx ? (31 - pi) : pi;
    const int q0 = qt << 6;
    const int kmax = q0 + 64;
    const int nIter = kmax >> 6;
    const int qwrow = q0 + wave * 16;
    const int qbase = qwrow + g * 4;
    short8 aq0, aq1;
    {
      const float* qp = Qg + bhSD + (size_t)(qwrow + m) * D_HEAD + g * 8;
      float4 x0 = *(const float4*)(qp);
      float4 x1 = *(const float4*)(qp + 4);
      float4 y0 = *(const float4*)(qp + 32);
      float4 y1 = *(const float4*)(qp + 36);
      aq0[0]=(short)f2b(x0.x*SCL); aq0[1]=(short)f2b(x0.y*SCL);
      aq0[2]=(short)f2b(x0.z*SCL); aq0[3]=(short)f2b(x0.w*SCL);
      aq0[4]=(short)f2b(x1.x*SCL); aq0[5]=(short)f2b(x1.y*SCL);
      aq0[6]=(short)f2b(x1.z*SCL); aq0[7]=(short)f2b(x1.w*SCL);
      aq1[0]=(short)f2b(y0.x*SCL); aq1[1]=(short)f2b(y0.y*SCL);
      aq1[2]=(short)f2b(y0.z*SCL); aq1[3]=(short)f2b(y0.w*SCL);
      aq1[4]=(short)f2b(y1.x*SCL); aq1[5]=(short)f2b(y1.y*SCL);
      aq1[6]=(short)f2b(y1.z*SCL); aq1[7]=(short)f2b(y1.w*SCL);
    }
    float rs0 = 0.f, rs1 = 0.f, rs2 = 0.f, rs3 = 0.f;
    {
      float4 kr[4];
      #pragma unroll
      for (int j = 0; j < 4; ++j)
        kr[j] = *(const float4*)(Kg + bhSD + (size_t)ss[j] * D_HEAD + dd[j]);
      #pragma unroll
      for (int j = 0; j < 4; ++j) {
        ushort4 kb;
        kb.x = f2b(kr[j].x); kb.y = f2b(kr[j].y);
        kb.z = f2b(kr[j].z); kb.w = f2b(kr[j].w);
        *(ushort4*)((char*)Kl[0] + koff[j]) = kb;
      }
    }
    __syncthreads();
    int cur = 0;
    for (int it = 0; it < nIter; ++it) {
      const int kc = it << 6;
      const bool pf = (it + 1 < nIter);
      float4 kr[4];
      if (pf) {
        #pragma unroll
        for (int j = 0; j < 4; ++j)
          kr[j] = *(const float4*)(Kg + bhSD + (size_t)(kc + 64 + ss[j]) * D_HEAD + dd[j]);
      }
      const char* KB = (const char*)Kl[cur];
      #pragma unroll
      for (int t = 0; t < 4; ++t) {
        f32x4 acc = {0.f, 0.f, 0.f, 0.f};
        const int rb = (t * 16 + m) << 7;
        short8 b0 = *(const short8*)(KB + ((rb + g * 16) ^ swzK));
        short8 b1 = *(const short8*)(KB + ((rb + 64 + g * 16) ^ swzK));
        acc = __builtin_amdgcn_mfma_f32_16x16x32_bf16(aq0, b0, acc, 0, 0, 0);
        acc = __builtin_amdgcn_mfma_f32_16x16x32_bf16(aq1, b1, acc, 0, 0, 0);
        const int kcol = kc + t * 16 + m;
        rs0 += (kcol <= qbase + 0) ? exp2f(acc[0]) : 0.f;
        rs1 += (kcol <= qbase + 1) ? exp2f(acc[1]) : 0.f;
        rs2 += (kcol <= qbase + 2) ? exp2f(acc[2]) : 0.f;
        rs3 += (kcol <= qbase + 3) ? exp2f(acc[3]) : 0.f;
      }
      if (pf) {
        #pragma unroll
        for (int j = 0; j < 4; ++j) {
          ushort4 kb;
          kb.x = f2b(kr[j].x); kb.y = f2b(kr[j].y);
          kb.z = f2b(kr[j].z); kb.w = f2b(kr[j].w);
          *(ushort4*)((char*)Kl[cur ^ 1] + koff[j]) = kb;
        }
      }
      __syncthreads();
      cur ^= 1;
    }
    #pragma unroll
    for (int sft = 1; sft < 16; sft <<= 1) {
      rs0 += __shfl_xor(rs0, sft, 64);
      rs1 += __shfl_xor(rs1, sft, 64);
      rs2 += __shfl_xor(rs2, sft, 64);
      rs3 += __shfl_xor(rs3, sft, 64);
    }
    const float ri0 = 1.f / rs0, ri1 = 1.f / rs1, ri2 = 1.f / rs2, ri3 = 1.f / rs3;
    f32x4 o0 = {0.f,0.f,0.f,0.f}, o1 = {0.f,0.f,0.f,0.f};
    f32x4 o2 = {0.f,0.f,0.f,0.f}, o3 = {0.f,0.f,0.f,0.f};
    {
      float4 kr[4], vr[4];
      #pragma unroll
      for (int j = 0; j < 4; ++j) {
        kr[j] = *(const float4*)(Kg + bhSD + (size_t)ss[j] * D_HEAD + dd[j]);
        vr[j] = *(const float4*)(Vg + bhSD + (size_t)ss[j] * D_HEAD + dd[j]);
      }
      #pragma unroll
      for (int j = 0; j < 4; ++j) {
        ushort4 kb;
        kb.x = f2b(kr[j].x); kb.y = f2b(kr[j].y);
        kb.z = f2b(kr[j].z); kb.w = f2b(kr[j].w);
        *(ushort4*)((char*)Kl[0] + koff[j]) = kb;
        const int d0 = dd[j], s2 = ss[j] << 1;
        char* VB1 = (char*)Vt[0];
        *(unsigned short*)(VB1 + ((((d0+0)<<7) + s2) ^ ((((d0+0)>>2)&7)<<4))) = f2b(vr[j].x);
        *(unsigned short*)(VB1 + ((((d0+1)<<7) + s2) ^ ((((d0+1)>>2)&7)<<4))) = f2b(vr[j].y);
        *(unsigned short*)(VB1 + ((((d0+2)<<7) + s2) ^ ((((d0+2)>>2)&7)<<4))) = f2b(vr[j].z);
        *(unsigned short*)(VB1 + ((((d0+3)<<7) + s2) ^ ((((d0+3)>>2)&7)<<4))) = f2b(vr[j].w);
      }
    }
    __syncthreads();
    cur = 0;
    for (int it = 0; it < nIter; ++it) {
      const int kc = it << 6;
      const bool pf = (it + 1 < nIter);
      float4 kr[4], vr[4];
      if (pf) {
        #pragma unroll
        for (int j = 0; j < 4; ++j) {
          kr[j] = *(const float4*)(Kg + bhSD + (size_t)(kc + 64 + ss[j]) * D_HEAD + dd[j]);
          vr[j] = *(const float4*)(Vg + bhSD + (size_t)(kc + 64 + ss[j]) * D_HEAD + dd[j]);
        }
      }
      const char* KB = (const char*)Kl[cur];
      const char* VB = (const char*)Vt[cur];
      float* arow = attn + bhSS + (size_t)qbase * S_LEN + kc;
      #pragma unroll
      for (int t = 0; t < 4; ++t) {
        f32x4 acc = {0.f, 0.f, 0.f, 0.f};
        const int rb = (t * 16 + m) << 7;
        short8 b0 = *(const short8*)(KB + ((rb + g * 16) ^ swzK));
        short8 b1 = *(const short8*)(KB + ((rb + 64 + g * 16) ^ swzK));
        acc = __builtin_amdgcn_mfma_f32_16x16x32_bf16(aq0, b0, acc, 0, 0, 0);
        acc = __builtin_amdgcn_mfma_f32_16x16x32_bf16(aq1, b1, acc, 0, 0, 0);
        const int kcol = kc + t * 16 + m;
        const int tc = t * 16 + m;
        float p0 = (kcol <= qbase + 0) ? exp2f(acc[0]) * ri0 : 0.f;
        float p1 = (kcol <= qbase + 1) ? exp2f(acc[1]) * ri1 : 0.f;
        float p2 = (kcol <= qbase + 2) ? exp2f(acc[2]) * ri2 : 0.f;
        float p3 = (kcol <= qbase + 3) ? exp2f(acc[3]) * ri3 : 0.f;
        arow[0 * S_LEN + tc] = p0;
        arow[1 * S_LEN + tc] = p1;
        arow[2 * S_LEN + tc] = p2;
        arow[3 * S_LEN + tc] = p3;
        const int r0 = g * 4, c2 = tc << 1;
        *(unsigned short*)(PB + ((((r0+0)<<7) + c2) ^ (((r0+0)&7)<<4))) = f2b(p0);
        *(unsigned short*)(PB + ((((r0+1)<<7) + c2) ^ (((r0+1)&7)<<4))) = f2b(p1);
        *(unsigned short*)(PB + ((((r0+2)<<7) + c2) ^ (((r0+2)&7)<<4))) = f2b(p2);
        *(unsigned short*)(PB + ((((r0+3)<<7) + c2) ^ (((r0+3)&7)<<4))) = f2b(p3);
      }
      short8 pa0 = *(const short8*)(PB + (((m << 7) + g * 16) ^ swzK));
      short8 pa1 = *(const short8*)(PB + (((m << 7) + 64 + g * 16) ^ swzK));
      #pragma unroll
      for (int dc = 0; dc < 4; ++dc) {
        short8 bv0 = *(const short8*)(VB + ((vro[dc] + g * 16) ^ vsz[dc]));
        short8 bv1 = *(const short8*)(VB + ((vro[dc] + 64 + g * 16) ^ vsz[dc]));
        f32x4& od = (dc == 0) ? o0 : (dc == 1) ? o1 : (dc == 2) ? o2 : o3;
        od = __builtin_amdgcn_mfma_f32_16x16x32_bf16(pa0, bv0, od, 0, 0, 0);
        od = __builtin_amdgcn_mfma_f32_16x16x32_bf16(pa1, bv1, od, 0, 0, 0);
      }
      if (pf) {
        #pragma unroll
        for (int j = 0; j < 4; ++j) {
          ushort4 kb;
          kb.x = f2b(kr[j].x); kb.y = f2b(kr[j].y);
          kb.z = f2b(kr[j].z); kb.w = f2b(kr[j].w);
          *(ushort4*)((char*)Kl[cur ^ 1] + koff[j]) = kb;
          const int d0 = dd[j], s2 = ss[j] << 1;
          char* VB1 = (char*)Vt[cur ^ 1];
          *(unsigned short*)(VB1 + ((((d0+0)<<7) + s2) ^ ((((d0+0)>>2)&7)<<4))) = f2b(vr[j].x);
          *(unsigned short*)(VB1 + ((((d0+1)<<7) + s2) ^ ((((d0+1)>>2)&7)<<4))) = f2b(vr[j].y);
          *(unsigned short*)(VB1 + ((((d0+2)<<7) + s2) ^ ((((d0+2)>>2)&7)<<4))) = f2b(vr[j].z);
          *(unsigned short*)(VB1 + ((((d0+3)<<7) + s2) ^ ((((d0+3)>>2)&7)<<4))) = f2b(vr[j].w);
        }
      }
      __syncthreads();
      cur ^= 1;
    }
    #pragma unroll
    for (int reg = 0; reg < 4; ++reg) {
      float* op = outp + bhSD + (size_t)(qbase + reg) * D_HEAD + m;
      op[ 0] = o0[reg];
      op[16] = o1[reg];
      op[32] = o2[reg];
      op[48] = o3[reg];
    }
    const int ncols = S_LEN - kmax;
    if (ncols > 0) {
      const float4 z = {0.f, 0.f, 0.f, 0.f};
      const int nvec = ncols >> 2;
      for (int r = 0; r < 64; ++r) {
        float4* rp = (float4*)(attn + bhSS + (size_t)(q0 + r) * S_LEN + kmax);
        for (int i = tid; i < nvec; i += 256) rp[i] = z;
      }
    }
  }
}

extern "C" void kernel_launch(void* const* d_in, const int* in_sizes, int n_in,
                              void* d_out, int out_size, void* d_ws, size_t ws_size,
                              hipStream_t stream) {
  (void)in_sizes; (void)n_in; (void)out_size;
  const float* q = (const float*)d_in[0];
  const float* k = (const float*)d_in[1];
  const float* v = (const float*)d_in[2];
  float* attn = (float*)d_out;
  float* outp = attn + (size_t)2 * 16 * 2048 * 2048;
  const size_t pre_bytes = (size_t)32 * NTILES * TILE_B;   // 8.39 MB per tensor
  if (ws_size >= 2 * pre_bytes) {
    char* Kpre = (char*)d_ws;
    char* Vpre = Kpre + pre_bytes;
    convert_kv_kernel<<<2048, 256, 0, stream>>>(k, v, Kpre, Vpre);
    sdpa_pre_kernel<<<1024, 256, 0, stream>>>(q, Kpre, Vpre, attn, outp);
  } else {
    sdpa_fb_kernel<<<512, 256, 0, stream>>>(q, k, v, attn, outp);
  }
}